// Round 8
// baseline (316.976 us; speedup 1.0000x reference)
//
#include <hip/hip_runtime.h>
#include <cstdint>
#include <cstddef>

#define S_LEN 384
#define BATCH 256
#define DIM   192     // HH*WW
#define HID   100
#define G4    400     // 4*HID
#define NCLS  250

#define LOG2E  1.4426950408889634f
#define LOG2E2 2.8853900817779268f

typedef float    f32x4   __attribute__((ext_vector_type(4)));
typedef short    bf16x8  __attribute__((ext_vector_type(8)));
typedef _Float16 half2_t __attribute__((ext_vector_type(2)));
typedef _Float16 f16x4   __attribute__((ext_vector_type(4)));
typedef _Float16 f16x8   __attribute__((ext_vector_type(8)));

static __device__ __forceinline__ unsigned short f2bf(float f) {
    unsigned u = __float_as_uint(f);
    return (unsigned short)((u + 0x7FFFu + ((u >> 16) & 1u)) >> 16);   // RN
}

// DPP quad_perm cross-lane (VALU ~2cyc)
template<int CTRL>
static __device__ __forceinline__ float fdpp(float x) {
    return __int_as_float(
        __builtin_amdgcn_mov_dpp(__float_as_int(x), CTRL, 0xF, 0xF, true));
}
#define DPP_X1 0xB1   // quad_perm [1,0,3,2]  == xor 1
#define DPP_X2 0x4E   // quad_perm [2,3,0,1]  == xor 2
#define DPP_B0 0x00   // quad_perm [0,0,0,0]  broadcast lane0 of quad
#define DPP_B1 0x55   // quad_perm [1,1,1,1]
#define DPP_B2 0xAA   // quad_perm [2,2,2,2]
#define DPP_B3 0xFF   // quad_perm [3,3,3,3]

// ---------------------------------------------------------------------------
// Prep (verified r1): blocks [0,300): Wt_bf[k=400][d=192] = bf16(W[d][k]);
//       blocks [300,382): Ut4 — per-thread-(n,q) U fragments for the
//       512-thr scan (4 lanes per unit, quarter-h each), XOR gate order.
// ---------------------------------------------------------------------------
__global__ void prep(const float* __restrict__ W, const float* __restrict__ U,
                     unsigned short* __restrict__ Wt, half2_t* __restrict__ Ut4)
{
    int bid = blockIdx.x;
    if (bid < 300) {
        int i = bid * 256 + threadIdx.x;             // 76800 elements
        if (i >= G4 * DIM) return;
        int k = i / DIM, d = i - k * DIM;
        Wt[i] = f2bf(W[(size_t)d * G4 + k]);
    } else {
        int i = (bid - 300) * 256 + threadIdx.x;     // 100*4*4*13 = 20800
        if (i >= 20800) return;
        int n    = i / 208;
        int rem  = i - n * 208;
        int q    = rem / 52;
        int rem2 = rem - q * 52;
        int m    = rem2 / 13;
        int r    = rem2 - m * 13;
        int col  = (q ^ m) * HID + n;
        int j0   = 26 * q + 2 * r;
        half2_t v;
        v.x = (_Float16)(j0     < HID ? U[(size_t)j0       * G4 + col] : 0.0f);
        v.y = (_Float16)(j0 + 1 < HID ? U[(size_t)(j0 + 1) * G4 + col] : 0.0f);
        Ut4[i] = v;
    }
}

// ---------------------------------------------------------------------------
// Kernel 1 (round 8): verified MFMA GEMM compute, NEW store path.
//   Old epilogue: 25 scattered 8B stores/lane at stride chunk*2B -> ~8x HBM
//   write amplification (~600MB effective for 78MB logical) — the ~100us.
//   New epilogue: stage C in LDS Cl[400][72] f16 (57.6KB, exactly reusing
//   the xs+wsh region after a barrier — LDS size unchanged, 2 blocks/CU
//   kept), then write preh rows coalesced: 400 rows x 128B contiguous,
//   8 lanes x dwordx4 per row.
// ---------------------------------------------------------------------------
__global__ __launch_bounds__(256, 2)
void gemm_pre(const float* __restrict__ x, const unsigned short* __restrict__ Wt,
              const float* __restrict__ bias, _Float16* __restrict__ preh,
              int s_start, int chunk)
{
    __shared__ __align__(16) unsigned char smem[57600];
    unsigned int* xs  = (unsigned int*)smem;             // 64*100 uint (25.6KB)
    unsigned int* wsh = (unsigned int*)(smem + 25600);   // 400*20 uint (32KB)
    _Float16*     Cl  = (_Float16*)smem;                 // 400*72 f16 (57.6KB) after reuse

    const int t    = threadIdx.x;
    const int lane = t & 63;
    const int w    = t >> 6;
    const int nsb  = chunk >> 6;
    const int b    = blockIdx.x / nsb;
    const int sblk = blockIdx.x - b * nsb;
    const float* __restrict__ xb = x + ((size_t)b * S_LEN + s_start + sblk * 64) * DIM;

#pragma unroll
    for (int r = 0; r < 12; ++r) {
        int i = t + r * 256;                 // 3072 float4 = 64 rows x 48
        int row = i / 48, c4 = i - row * 48;
        float4 v = ((const float4*)(xb + (size_t)row * DIM))[c4];
        xs[row * 100 + c4 * 2]     = (unsigned)f2bf(v.x) | ((unsigned)f2bf(v.y) << 16);
        xs[row * 100 + c4 * 2 + 1] = (unsigned)f2bf(v.z) | ((unsigned)f2bf(v.w) << 16);
    }

    const int m = lane & 15, q = lane >> 4;

    float bv[25];
#pragma unroll
    for (int ct = 0; ct < 25; ++ct) bv[ct] = bias[ct * 16 + m];

    f32x4 acc[25];
#pragma unroll
    for (int ct = 0; ct < 25; ++ct) acc[ct] = (f32x4){0.f, 0.f, 0.f, 0.f};

    for (int dc = 0; dc < 6; ++dc) {
        if (dc) __syncthreads();             // protect previous chunk's readers
#pragma unroll
        for (int r = 0; r < 7; ++r) {
            int i = t + r * 256;
            if (i < 1600) {                  // 400 rows x 4 uint4 (32 bf16 = 64B)
                int k = i >> 2, u4 = i & 3;
                uint4 v = *(const uint4*)(Wt + (size_t)k * DIM + dc * 32 + u4 * 8);
                *(uint4*)(wsh + k * 20 + u4 * 4) = v;
            }
        }
        __syncthreads();

        const unsigned short* xp = (const unsigned short*)xs
                                   + (16 * w + m) * 200 + dc * 32 + q * 8;
        bf16x8 af = *(const bf16x8*)xp;
#pragma unroll
        for (int ct = 0; ct < 25; ++ct) {
            const unsigned short* bp = (const unsigned short*)wsh
                                       + (ct * 16 + m) * 40 + q * 8;
            bf16x8 bf = *(const bf16x8*)bp;
            acc[ct] = __builtin_amdgcn_mfma_f32_16x16x32_bf16(af, bf, acc[ct], 0, 0, 0);
        }
    }

    // ---- NEW epilogue: LDS transpose staging + coalesced stores ----
    __syncthreads();                         // all waves done reading xs/wsh
#pragma unroll
    for (int ct = 0; ct < 25; ++ct) {
        // lane holds k = ct*16+m, s = 16w + q*4 + e  (verified D mapping)
        f16x4 v;
        v[0] = (_Float16)(acc[ct][0] + bv[ct]);
        v[1] = (_Float16)(acc[ct][1] + bv[ct]);
        v[2] = (_Float16)(acc[ct][2] + bv[ct]);
        v[3] = (_Float16)(acc[ct][3] + bv[ct]);
        *(f16x4*)&Cl[(ct * 16 + m) * 72 + 16 * w + q * 4] = v;   // 8B, 8B-aligned
    }
    __syncthreads();

    _Float16* __restrict__ pb = preh + (size_t)b * G4 * chunk + (size_t)sblk * 64;
    const int lane8 = t & 7, rbase = t >> 3;
#pragma unroll
    for (int p = 0; p < 13; ++p) {
        int r = p * 32 + rbase;              // k row
        if (r < G4) {
            f16x8 vv = *(const f16x8*)&Cl[r * 72 + lane8 * 8];   // 16B, 16B-aligned
            *(f16x8*)(pb + (size_t)r * chunk + lane8 * 8) = vv;  // coalesced 128B/row
        }
    }
}

// ---------------------------------------------------------------------------
// Kernel 2: the VERIFIED r1 scan (176.3us), byte-identical.
// ---------------------------------------------------------------------------
__global__ __launch_bounds__(512, 2)
void lstm_scan(const _Float16* __restrict__ preh, const half2_t* __restrict__ Ut4,
               const float* __restrict__ Wd, const float* __restrict__ bd,
               float* __restrict__ out, float* __restrict__ state,
               int nsteps, int first, int last)
{
    __shared__ __align__(16) _Float16 h2[2][4][40];
    __shared__ __align__(16) float hf32[HID];

    const int b  = blockIdx.x;
    const int t  = threadIdx.x;
    const int q  = t & 3;
    const int nr = t >> 2;                   // 0..127
    const bool active = (nr < HID);
    const int n  = active ? nr : HID - 1;
    const int wq = n / 26, wi = n - wq * 26;

    half2_t Uc[4][13];
#pragma unroll
    for (int m = 0; m < 4; ++m) {
        const half2_t* up = Ut4 + (size_t)((n * 4 + q) * 4 + m) * 13;
#pragma unroll
        for (int r = 0; r < 13; ++r) Uc[m][r] = up[r];
    }

    if (t < 320) ((_Float16*)h2)[t] = (_Float16)0.f;
    float c;
    if (first) {
        c = 0.f;
        __syncthreads();
    } else {
        c = state[BATCH * HID + b * HID + n];
        __syncthreads();
        if (t < HID) h2[0][t / 26][t - (t / 26) * 26] = (_Float16)state[b * HID + t];
        __syncthreads();
    }

    const _Float16* __restrict__ zp = preh + ((size_t)b * G4 + q * HID + n) * nsteps;

    const float scale = (q == 2) ? -LOG2E2 : -LOG2E;
    const float Aact  = (q == 2) ? 2.0f : 1.0f;
    const float Bact  = (q == 2) ? -1.0f : 0.0f;

    float hn_last = 0.f;

    auto step = [&](float zk, int cur) {
        const _Float16* hb = &h2[cur][q][0];
        f16x8   g0 = *(const f16x8*)(hb);
        f16x8   g1 = *(const f16x8*)(hb + 8);
        f16x8   g2 = *(const f16x8*)(hb + 16);
        half2_t g3 = *(const half2_t*)(hb + 24);
        half2_t hp[13];
        hp[0]  = __builtin_shufflevector(g0, g0, 0, 1);
        hp[1]  = __builtin_shufflevector(g0, g0, 2, 3);
        hp[2]  = __builtin_shufflevector(g0, g0, 4, 5);
        hp[3]  = __builtin_shufflevector(g0, g0, 6, 7);
        hp[4]  = __builtin_shufflevector(g1, g1, 0, 1);
        hp[5]  = __builtin_shufflevector(g1, g1, 2, 3);
        hp[6]  = __builtin_shufflevector(g1, g1, 4, 5);
        hp[7]  = __builtin_shufflevector(g1, g1, 6, 7);
        hp[8]  = __builtin_shufflevector(g2, g2, 0, 1);
        hp[9]  = __builtin_shufflevector(g2, g2, 2, 3);
        hp[10] = __builtin_shufflevector(g2, g2, 4, 5);
        hp[11] = __builtin_shufflevector(g2, g2, 6, 7);
        hp[12] = g3;

        float p0 = 0.f, p1 = 0.f, p2 = 0.f, p3 = 0.f;
#pragma unroll
        for (int r = 0; r < 13; ++r) {
            p0 = __builtin_amdgcn_fdot2(Uc[0][r], hp[r], p0, false);
            p1 = __builtin_amdgcn_fdot2(Uc[1][r], hp[r], p1, false);
            p2 = __builtin_amdgcn_fdot2(Uc[2][r], hp[r], p2, false);
            p3 = __builtin_amdgcn_fdot2(Uc[3][r], hp[r], p3, false);
        }
        float s0 = p0 + fdpp<DPP_X1>(p1);
        float s2 = p2 + fdpp<DPP_X1>(p3);
        float a  = s0 + fdpp<DPP_X2>(s2) + zk;

        float v = fmaf(Aact,
                       __builtin_amdgcn_rcpf(1.0f + __builtin_amdgcn_exp2f(scale * a)),
                       Bact);

        float bi = fdpp<DPP_B0>(v);
        float bf = fdpp<DPP_B1>(v);
        float bg = fdpp<DPP_B2>(v);
        float bo = fdpp<DPP_B3>(v);

        c = fmaf(bf, c, bi * bg);
        float tc = fmaf(2.0f,
                        __builtin_amdgcn_rcpf(1.0f + __builtin_amdgcn_exp2f(-LOG2E2 * c)),
                        -1.0f);
        float hn = bo * tc;
        if (q == 0 && active) h2[cur ^ 1][wq][wi] = (_Float16)hn;
        hn_last = hn;
        __syncthreads();
    };

    f16x8 zv = *(const f16x8*)(zp);
    for (int s8 = 0; s8 < nsteps; s8 += 8) {            // nsteps % 8 == 0
        f16x8 zvn = zv;
        if (s8 + 8 < nsteps) zvn = *(const f16x8*)(zp + s8 + 8);   // prefetch
#pragma unroll
        for (int k = 0; k < 8; ++k)
            step((float)zv[k], k & 1);
        zv = zvn;
    }

    if (last) {
        if (q == 0 && active) hf32[n] = hn_last;
        __syncthreads();
        if (t < NCLS) {
            float acc2 = bd[t];
            const float4* h4 = (const float4*)hf32;
#pragma unroll 5
            for (int j4 = 0; j4 < 25; ++j4) {
                float4 hv = h4[j4];
                acc2 = fmaf(hv.x, Wd[(size_t)(4 * j4 + 0) * NCLS + t], acc2);
                acc2 = fmaf(hv.y, Wd[(size_t)(4 * j4 + 1) * NCLS + t], acc2);
                acc2 = fmaf(hv.z, Wd[(size_t)(4 * j4 + 2) * NCLS + t], acc2);
                acc2 = fmaf(hv.w, Wd[(size_t)(4 * j4 + 3) * NCLS + t], acc2);
            }
            out[(size_t)b * NCLS + t] = acc2;
        }
    } else {
        if (q == 0 && active) {
            state[b * HID + n] = hn_last;
            state[BATCH * HID + b * HID + n] = c;
        }
    }
}

// ---------------------------------------------------------------------------
extern "C" void kernel_launch(void* const* d_in, const int* in_sizes, int n_in,
                              void* d_out, int out_size, void* d_ws, size_t ws_size,
                              hipStream_t stream)
{
    const float* x    = (const float*)d_in[0];
    const float* W    = (const float*)d_in[1];
    const float* U    = (const float*)d_in[2];
    const float* bias = (const float*)d_in[3];
    const float* Wd   = (const float*)d_in[4];
    const float* bd   = (const float*)d_in[5];
    float* out = (float*)d_out;

    // ws (dwords): [state 51200][Ut4 20800][Wt_bf 38400][preh f16: chunk*51200 dw]
    const size_t fixed_dw = 51200 + 20800 + 38400;   // 110400
    int chunk = 64;
    if      (ws_size >= (fixed_dw + (size_t)384 * 51200) * 4) chunk = 384;
    else if (ws_size >= (fixed_dw + (size_t)192 * 51200) * 4) chunk = 192;
    const int nchunks = S_LEN / chunk;

    unsigned int* wsb = (unsigned int*)d_ws;
    float*          state = (float*)wsb;
    half2_t*        Ut4   = (half2_t*)(wsb + 51200);
    unsigned short* Wt    = (unsigned short*)(wsb + 72000);
    _Float16*       preh  = (_Float16*)(wsb + 110400);

    prep<<<382, 256, 0, stream>>>(W, U, Wt, Ut4);

    for (int ci = 0; ci < nchunks; ++ci) {
        const int s0 = ci * chunk;
        gemm_pre<<<BATCH * (chunk >> 6), 256, 0, stream>>>(x, Wt, bias, preh, s0, chunk);
        lstm_scan<<<BATCH, 512, 0, stream>>>(preh, Ut4, Wd, bd, out, state,
                                             chunk, ci == 0 ? 1 : 0,
                                             ci == nchunks - 1 ? 1 : 0);
    }
}